// Round 1
// 651.127 us; speedup vs baseline: 1.0500x; 1.0500x over previous
//
#include <hip/hip_runtime.h>
#include <hip/hip_bf16.h>
#include <stdint.h>

#define D_MODEL 1024
#define NHEADS  8
#define DKH     128
#define DFF     4096
#define SEQ     2048
#define BATCH   4
#define NTOK    (BATCH*SEQ)   // 8192
#define QKS     2048          // row stride of fused QK buffer

typedef float  f32x4  __attribute__((ext_vector_type(4)));
typedef __bf16 bf16x8 __attribute__((ext_vector_type(8)));

static __device__ __forceinline__ float b2f(ushort u) {
    union { uint32_t i; float f; } v; v.i = ((uint32_t)u) << 16; return v.f;
}
static __device__ __forceinline__ ushort f2b(float f) {
    union { float f; uint32_t i; } v; v.f = f;
    uint32_t r = v.i + 0x7fffu + ((v.i >> 16) & 1u);
    return (ushort)(r >> 16);
}
static __device__ __forceinline__ void gl_lds16(const void* g, void* l) {
    __builtin_amdgcn_global_load_lds(
        (const __attribute__((address_space(1))) void*)g,
        (__attribute__((address_space(3))) void*)l, 16, 0, 0);
}
// XOR-swizzled index for [rows][72] LDS tiles (manual writes, e.g. Ps)
static __device__ __forceinline__ int swz72(int row, int col) {
    return row * 72 + ((((col >> 3) ^ (row >> 3)) & 7) << 3) + (col & 7);
}

// ---------------------------------------------------------------------------
__global__ __launch_bounds__(256) void conv_kernel(
    const float* __restrict__ in, ushort* __restrict__ out, int n)
{
    for (int i = (blockIdx.x * 256 + threadIdx.x) * 4; i < n; i += gridDim.x * 1024) {
        float4 v = *(const float4*)(in + i);
        ushort o[4] = { f2b(v.x), f2b(v.y), f2b(v.z), f2b(v.w) };
        *(uint2*)(out + i) = *(const uint2*)o;
    }
}

// transpose + convert: fp32 [R][C] -> bf16 [C][R]
__global__ __launch_bounds__(256) void tconv_kernel(
    const float* __restrict__ in, ushort* __restrict__ out, int R, int C)
{
    __shared__ float L[32][33];
    const int tid = threadIdx.x;
    const int tx = tid & 31, ty = tid >> 5;
    const int nbc = C >> 5;
    const int r0 = (blockIdx.x / nbc) << 5;
    const int c0 = (blockIdx.x % nbc) << 5;
    #pragma unroll
    for (int p = 0; p < 4; ++p)
        L[ty + 8 * p][tx] = in[(size_t)(r0 + ty + 8 * p) * C + c0 + tx];
    __syncthreads();
    #pragma unroll
    for (int p = 0; p < 4; ++p)
        out[(size_t)(c0 + ty + 8 * p) * R + r0 + tx] = f2b(L[tx][ty + 8 * p]);
}

__global__ __launch_bounds__(256) void cat3_kernel(
    const float* __restrict__ a, const float* __restrict__ b,
    const float* __restrict__ c, float* __restrict__ out)
{
    const int i = blockIdx.x * 256 + threadIdx.x;
    out[i] = (i < 1024) ? a[i] : (i < 2048) ? b[i - 1024] : c[i - 2048];
}

// ---------------------------------------------------------------------------
// GEMM: C = A @ Bt^T + bias. 128x128 tile, BK=32, global_load_lds w=16.
// MODE 0: plain (C stride N); MODE 1: ReLU; MODE 2: QKV-split — n<2048 goes
// to qk buffer (stride 2048), n>=2048 written TRANSPOSED into vt[b,h,d,s].
// ---------------------------------------------------------------------------
template<int MODE>
__global__ __launch_bounds__(256) void gemm_bt(
    const ushort* __restrict__ A, const ushort* __restrict__ Bt,
    const float* __restrict__ bias, ushort* __restrict__ C,
    int M, int N, int K, ushort* __restrict__ vt)
{
    __shared__ __align__(16) ushort As[128 * 32];
    __shared__ __align__(16) ushort Bs[128 * 32];

    const int tid  = threadIdx.x;
    const int w    = tid >> 6;
    const int lane = tid & 63;
    const int l16  = lane & 15;
    const int quad = lane >> 4;

    const int nbn = N >> 7;
    const int m0  = (blockIdx.x / nbn) << 7;
    const int n0  = (blockIdx.x % nbn) << 7;

    const int wm = (w >> 1) << 6;
    const int wn = (w & 1) << 6;

    const int srow = (w << 5) + (lane >> 2);
    const int scol = (lane & 3) << 3;
    const ushort* Ag = A  + (size_t)(m0 + srow) * K + scol;
    const ushort* Bg = Bt + (size_t)(n0 + srow) * K + scol;
    ushort* Asw = &As[(w << 5) * 32];
    ushort* Bsw = &Bs[(w << 5) * 32];

    f32x4 acc[4][4] = {};

    for (int k0 = 0; k0 < K; k0 += 32) {
        __syncthreads();
        gl_lds16(Ag + k0,                  Asw);
        gl_lds16(Ag + k0 + (size_t)16 * K, Asw + 16 * 32);
        gl_lds16(Bg + k0,                  Bsw);
        gl_lds16(Bg + k0 + (size_t)16 * K, Bsw + 16 * 32);
        __syncthreads();

        bf16x8 af[4], bf[4];
        #pragma unroll
        for (int i = 0; i < 4; ++i) {
            af[i] = *(const bf16x8*)&As[(wm + i * 16 + l16) * 32 + (quad << 3)];
            bf[i] = *(const bf16x8*)&Bs[(wn + i * 16 + l16) * 32 + (quad << 3)];
        }
        #pragma unroll
        for (int mt = 0; mt < 4; ++mt)
            #pragma unroll
            for (int nt = 0; nt < 4; ++nt)
                acc[mt][nt] = __builtin_amdgcn_mfma_f32_16x16x32_bf16(
                    af[mt], bf[nt], acc[mt][nt], 0, 0, 0);
    }

    if (MODE == 2 && n0 >= 2048) {
        // V part -> vt[(b*8+h)*128 + d][s]
        #pragma unroll
        for (int nt = 0; nt < 4; ++nt) {
            const int n  = n0 + wn + (nt << 4) + l16;
            const int hd = n - 2048;
            const float bv = bias[n];
            const size_t vrow = (size_t)(hd >> 7) * 128 + (hd & 127);
            #pragma unroll
            for (int mt = 0; mt < 4; ++mt) {
                const int m = m0 + wm + (mt << 4) + (quad << 2);
                const size_t row = (size_t)(m >> 11) * 1024 + vrow;
                ushort pk[4];
                #pragma unroll
                for (int r = 0; r < 4; ++r) pk[r] = f2b(acc[mt][nt][r] + bv);
                *(uint2*)(vt + row * SEQ + (m & 2047)) = *(const uint2*)pk;
            }
        }
    } else {
        const int ldc = (MODE == 2) ? QKS : N;
        #pragma unroll
        for (int nt = 0; nt < 4; ++nt) {
            const int n = n0 + wn + (nt << 4) + l16;
            const float bv = bias[n];
            #pragma unroll
            for (int mt = 0; mt < 4; ++mt) {
                #pragma unroll
                for (int r = 0; r < 4; ++r) {
                    const int m = m0 + wm + (mt << 4) + (quad << 2) + r;
                    float v = acc[mt][nt][r] + bv;
                    if (MODE == 1) v = fmaxf(v, 0.f);
                    C[(size_t)m * ldc + n] = f2b(v);
                }
            }
        }
    }
}

// ---------------------------------------------------------------------------
// Split-K GEMM (2 slices, one dispatch): C_sl = A[:,ksl] @ Bt[:,ksl]^T
// bias added to slice 0 only; bf16 partials summed in LN2.
// ---------------------------------------------------------------------------
__global__ __launch_bounds__(256) void gemm_bt_sk(
    const ushort* __restrict__ A, const ushort* __restrict__ Bt,
    const float* __restrict__ bias, ushort* __restrict__ C0,
    ushort* __restrict__ C1, int M, int N, int K)
{
    __shared__ __align__(16) ushort As[128 * 32];
    __shared__ __align__(16) ushort Bs[128 * 32];

    const int tiles = (M >> 7) * (N >> 7);
    const int sl  = blockIdx.x / tiles;
    const int tix = blockIdx.x % tiles;
    const int kbeg = sl * (K >> 1);
    const int kend = kbeg + (K >> 1);

    const int tid  = threadIdx.x;
    const int w    = tid >> 6;
    const int lane = tid & 63;
    const int l16  = lane & 15;
    const int quad = lane >> 4;

    const int nbn = N >> 7;
    const int m0  = (tix / nbn) << 7;
    const int n0  = (tix % nbn) << 7;

    const int wm = (w >> 1) << 6;
    const int wn = (w & 1) << 6;

    const int srow = (w << 5) + (lane >> 2);
    const int scol = (lane & 3) << 3;
    const ushort* Ag = A  + (size_t)(m0 + srow) * K + scol;
    const ushort* Bg = Bt + (size_t)(n0 + srow) * K + scol;
    ushort* Asw = &As[(w << 5) * 32];
    ushort* Bsw = &Bs[(w << 5) * 32];

    f32x4 acc[4][4] = {};

    for (int k0 = kbeg; k0 < kend; k0 += 32) {
        __syncthreads();
        gl_lds16(Ag + k0,                  Asw);
        gl_lds16(Ag + k0 + (size_t)16 * K, Asw + 16 * 32);
        gl_lds16(Bg + k0,                  Bsw);
        gl_lds16(Bg + k0 + (size_t)16 * K, Bsw + 16 * 32);
        __syncthreads();

        bf16x8 af[4], bf[4];
        #pragma unroll
        for (int i = 0; i < 4; ++i) {
            af[i] = *(const bf16x8*)&As[(wm + i * 16 + l16) * 32 + (quad << 3)];
            bf[i] = *(const bf16x8*)&Bs[(wn + i * 16 + l16) * 32 + (quad << 3)];
        }
        #pragma unroll
        for (int mt = 0; mt < 4; ++mt)
            #pragma unroll
            for (int nt = 0; nt < 4; ++nt)
                acc[mt][nt] = __builtin_amdgcn_mfma_f32_16x16x32_bf16(
                    af[mt], bf[nt], acc[mt][nt], 0, 0, 0);
    }

    ushort* C = sl ? C1 : C0;
    #pragma unroll
    for (int nt = 0; nt < 4; ++nt) {
        const int n = n0 + wn + (nt << 4) + l16;
        const float bv = sl ? 0.f : bias[n];
        #pragma unroll
        for (int mt = 0; mt < 4; ++mt) {
            #pragma unroll
            for (int r = 0; r < 4; ++r) {
                const int m = m0 + wm + (mt << 4) + (quad << 2) + r;
                C[(size_t)m * N + n] = f2b(acc[mt][nt][r] + bv);
            }
        }
    }
}

// ---------------------------------------------------------------------------
// Flash attention v2: Q-tile 64 (1 strip), KV-tile 64, K/V DOUBLE-BUFFERED.
// One barrier per tile: [barrier] -> issue stage(t+1) into buf^1 -> compute(t).
// The next barrier's implicit vmcnt(0) drains loads that flew during the
// whole compute phase (issue-early pipeline, no inline asm needed).
// Grid = 1024 blocks (2x previous) with bijective XCD swizzle so the 32
// blocks sharing one (b,h)'s K/V land on the same XCD L2.
// LDS: Ks[2][64][128] + Vs[2][128][64] + Ps[64][72] = 73 KB -> 2 blocks/CU.
// ---------------------------------------------------------------------------
__global__ __launch_bounds__(256) void attn_kernel(
    ushort* __restrict__ qk, const ushort* __restrict__ vt)
{
    __shared__ __align__(16) ushort smem[37376];
    ushort* Ks0 = smem;            // [64][128] grp16 swizzle, slot 0
    ushort* Ks1 = smem + 8192;     // slot 1 (Q staging area in prologue)
    ushort* Vs0 = smem + 16384;    // [128][64] grp8 swizzle (rows = d), slot 0
    ushort* Vs1 = smem + 24576;    // slot 1
    ushort* Ps  = smem + 32768;    // [64][72] swz72

    const int tid  = threadIdx.x;
    const int w    = tid >> 6;
    const int lane = tid & 63;
    const int l16  = lane & 15;
    const int quad = lane >> 4;

    // XCD-aware bijective swizzle: 1024 blocks, 8 XCDs -> XCD x owns
    // contiguous work ids [x*128, x*128+128) = 4 whole (b,h) groups.
    const int bid = ((blockIdx.x & 7) << 7) + (blockIdx.x >> 3);
    const int qb  = bid & 31;
    const int h   = (bid >> 5) & 7;
    const int b   = bid >> 8;

    ushort* Qp = qk + ((size_t)(b * SEQ + qb * 64)) * QKS + h * DKH;
    const ushort* Kp = qk + ((size_t)(b * SEQ)) * QKS + 1024 + h * DKH;
    const ushort* Vp = vt + ((size_t)((b * 8 + h) * 128)) * SEQ;

    // ---- prologue: issue Q -> Ks1, K[0] -> Ks0, V[0] -> Vs0, then drain ----
    #pragma unroll
    for (int i = 0; i < 4; ++i) {
        const int row = w * 16 + i * 4 + quad;
        const int g = (l16 & 8) | ((l16 & 7) ^ (row & 7));
        gl_lds16(Qp + (size_t)row * QKS + g * 8, Ks1 + (w * 16 + i * 4) * 128);
    }
    #pragma unroll
    for (int i = 0; i < 4; ++i) {          // K[0]
        const int row = w * 16 + i * 4 + quad;
        const int g = (l16 & 8) | ((l16 & 7) ^ (row & 7));
        gl_lds16(Kp + (size_t)row * QKS + g * 8, Ks0 + (w * 16 + i * 4) * 128);
    }
    #pragma unroll
    for (int i = 0; i < 4; ++i) {          // V[0]
        const int d = w * 32 + i * 8 + (lane >> 3);
        const int g = (lane & 7) ^ (d & 7);
        gl_lds16(Vp + (size_t)d * SEQ + g * 8, Vs0 + (w * 32 + i * 8) * 64);
    }
    __syncthreads();

    // Q fragments from Ks1 (ds_reads complete before the t=0 barrier,
    // so staging K[1] into Ks1 afterwards is safe)
    bf16x8 aq[4];
    {
        const int r = w * 16 + l16;
        #pragma unroll
        for (int kq = 0; kq < 4; ++kq) {
            const int gk = kq * 4 + quad;
            const int g = (gk & 8) | ((gk & 7) ^ (r & 7));
            aq[kq] = *(const bf16x8*)&Ks1[r * 128 + g * 8];
        }
    }

    f32x4 o[8] = {};
    float mrun[4], lrun[4];
    #pragma unroll
    for (int r = 0; r < 4; ++r) { mrun[r] = -1e30f; lrun[r] = 0.f; }

    const float scale = 0.08838834764831845f;   // 1/sqrt(128)

    for (int t = 0; t < SEQ / 64; ++t) {
        __syncthreads();   // t's buffers ready (implicit vmcnt(0)); prev reads done

        // issue next tile's staging into the other buffer; flies during compute
        if (t + 1 < SEQ / 64) {
            ushort* Ksn = (t & 1) ? Ks0 : Ks1;
            ushort* Vsn = (t & 1) ? Vs0 : Vs1;
            #pragma unroll
            for (int i = 0; i < 4; ++i) {
                const int row = w * 16 + i * 4 + quad;
                const int g = (l16 & 8) | ((l16 & 7) ^ (row & 7));
                gl_lds16(Kp + ((size_t)((t + 1) * 64 + row)) * QKS + g * 8,
                         Ksn + (w * 16 + i * 4) * 128);
            }
            #pragma unroll
            for (int i = 0; i < 4; ++i) {
                const int d = w * 32 + i * 8 + (lane >> 3);
                const int g = (lane & 7) ^ (d & 7);
                gl_lds16(Vp + (size_t)d * SEQ + (t + 1) * 64 + g * 8,
                         Vsn + (w * 32 + i * 8) * 64);
            }
        }
        ushort* Ksc = (t & 1) ? Ks1 : Ks0;
        ushort* Vsc = (t & 1) ? Vs1 : Vs0;

        // S = (Q K^T) * scale
        f32x4 s[4] = {};
        #pragma unroll
        for (int nt = 0; nt < 4; ++nt) {
            const int rk = nt * 16 + l16;
            #pragma unroll
            for (int kq = 0; kq < 4; ++kq) {
                const int gk = kq * 4 + quad;
                const int g = (gk & 8) | ((gk & 7) ^ (rk & 7));
                bf16x8 bk = *(const bf16x8*)&Ksc[rk * 128 + g * 8];
                s[nt] = __builtin_amdgcn_mfma_f32_16x16x32_bf16(aq[kq], bk, s[nt], 0, 0, 0);
            }
        }
        #pragma unroll
        for (int nt = 0; nt < 4; ++nt) s[nt] *= scale;

        // online softmax
        float alpha[4];
        #pragma unroll
        for (int r = 0; r < 4; ++r) {
            float v = fmaxf(fmaxf(s[0][r], s[1][r]), fmaxf(s[2][r], s[3][r]));
            #pragma unroll
            for (int msk = 1; msk <= 8; msk <<= 1)
                v = fmaxf(v, __shfl_xor(v, msk, 64));
            const float mnew = fmaxf(mrun[r], v);
            alpha[r] = __expf(mrun[r] - mnew);
            mrun[r] = mnew;
        }
        float sum[4] = {};
        #pragma unroll
        for (int nt = 0; nt < 4; ++nt)
            #pragma unroll
            for (int r = 0; r < 4; ++r) {
                const float p = __expf(s[nt][r] - mrun[r]);
                sum[r] += p;
                Ps[swz72(w * 16 + (quad << 2) + r, nt * 16 + l16)] = f2b(p);
            }
        #pragma unroll
        for (int r = 0; r < 4; ++r) {
            float v = sum[r];
            #pragma unroll
            for (int msk = 1; msk <= 8; msk <<= 1)
                v += __shfl_xor(v, msk, 64);
            lrun[r] = lrun[r] * alpha[r] + v;
        }
        #pragma unroll
        for (int nt8 = 0; nt8 < 8; ++nt8)
            #pragma unroll
            for (int r = 0; r < 4; ++r)
                o[nt8][r] *= alpha[r];

        // O += P V (Ps rows are own-wave; Vs synced by the tile barrier)
        #pragma unroll
        for (int kp = 0; kp < 2; ++kp) {
            bf16x8 ap = *(const bf16x8*)&Ps[swz72(w * 16 + l16, kp * 32 + (quad << 3))];
            const int gkv = kp * 4 + quad;
            #pragma unroll
            for (int nt8 = 0; nt8 < 8; ++nt8) {
                const int d = nt8 * 16 + l16;
                bf16x8 bv = *(const bf16x8*)&Vsc[d * 64 + ((gkv ^ (d & 7)) << 3)];
                o[nt8] = __builtin_amdgcn_mfma_f32_16x16x32_bf16(ap, bv, o[nt8], 0, 0, 0);
            }
        }
    }

    #pragma unroll
    for (int r = 0; r < 4; ++r) {
        const float inv = 1.f / lrun[r];
        const int row = w * 16 + (quad << 2) + r;
        #pragma unroll
        for (int nt8 = 0; nt8 < 8; ++nt8)
            Qp[(size_t)row * QKS + nt8 * 16 + l16] = f2b(o[nt8][r] * inv);
    }
}

// ---------------------------------------------------------------------------
// Residual-add + LayerNorm. a bf16 (stride astride); a2 optional bf16 partial
// (stride 1024); res bf16 or fp32; g/be fp32; out bf16 or fp32.
// ---------------------------------------------------------------------------
__global__ __launch_bounds__(256) void ln_kernel(
    const ushort* __restrict__ a, int astride, const ushort* __restrict__ a2,
    const void* __restrict__ res, int res_f32,
    const float* __restrict__ g, const float* __restrict__ be,
    void* __restrict__ out, int out_f32)
{
    __shared__ float red[8];
    const int row = blockIdx.x;
    const int tid = threadIdx.x;
    const int col = tid * 4;

    ushort av[4];
    *(uint2*)av = *(const uint2*)(a + (size_t)row * astride + col);

    float v[4];
    if (res_f32) {
        float4 rr = *(const float4*)((const float*)res + (size_t)row * D_MODEL + col);
        v[0] = b2f(av[0]) + rr.x; v[1] = b2f(av[1]) + rr.y;
        v[2] = b2f(av[2]) + rr.z; v[3] = b2f(av[3]) + rr.w;
    } else {
        ushort rv[4];
        *(uint2*)rv = *(const uint2*)((const ushort*)res + (size_t)row * D_MODEL + col);
        #pragma unroll
        for (int i = 0; i < 4; ++i) v[i] = b2f(av[i]) + b2f(rv[i]);
    }
    if (a2) {
        ushort bv[4];
        *(uint2*)bv = *(const uint2*)(a2 + (size_t)row * D_MODEL + col);
        #pragma unroll
        for (int i = 0; i < 4; ++i) v[i] += b2f(bv[i]);
    }

    float s = v[0] + v[1] + v[2] + v[3];
    #pragma unroll
    for (int m = 1; m <= 32; m <<= 1) s += __shfl_xor(s, m, 64);
    if ((tid & 63) == 0) red[tid >> 6] = s;
    __syncthreads();
    const float mu = (red[0] + red[1] + red[2] + red[3]) * (1.f / D_MODEL);

    float q = 0.f;
    #pragma unroll
    for (int i = 0; i < 4; ++i) { const float d = v[i] - mu; q += d * d; }
    #pragma unroll
    for (int m = 1; m <= 32; m <<= 1) q += __shfl_xor(q, m, 64);
    if ((tid & 63) == 0) red[4 + (tid >> 6)] = q;
    __syncthreads();
    const float var = (red[4] + red[5] + red[6] + red[7]) * (1.f / D_MODEL);
    const float rstd = rsqrtf(var + 1e-6f);

    float4 gg = *(const float4*)(g + col);
    float4 bb = *(const float4*)(be + col);
    float y[4];
    y[0] = (v[0] - mu) * rstd * gg.x + bb.x;
    y[1] = (v[1] - mu) * rstd * gg.y + bb.y;
    y[2] = (v[2] - mu) * rstd * gg.z + bb.z;
    y[3] = (v[3] - mu) * rstd * gg.w + bb.w;

    if (out_f32) {
        float4 ov; ov.x = y[0]; ov.y = y[1]; ov.z = y[2]; ov.w = y[3];
        *(float4*)((float*)out + (size_t)row * D_MODEL + col) = ov;
    } else {
        ushort ov[4] = { f2b(y[0]), f2b(y[1]), f2b(y[2]), f2b(y[3]) };
        *(uint2*)((ushort*)out + (size_t)row * D_MODEL + col) = *(const uint2*)ov;
    }
}

__global__ __launch_bounds__(256) void sentinel_kernel(float* out, float S, int n) {
    for (int i = blockIdx.x * 256 + threadIdx.x; i < n; i += gridDim.x * 256)
        out[i] = S;
}

// ---------------------------------------------------------------------------
extern "C" void kernel_launch(void* const* d_in, const int* in_sizes, int n_in,
                              void* d_out, int out_size, void* d_ws, size_t ws_size,
                              hipStream_t stream)
{
    const float* x   = (const float*)d_in[0];
    const float* Wq  = (const float*)d_in[1];
    const float* bq  = (const float*)d_in[2];
    const float* Wk  = (const float*)d_in[3];
    const float* bk  = (const float*)d_in[4];
    const float* Wv  = (const float*)d_in[5];
    const float* bv  = (const float*)d_in[6];
    const float* g1  = (const float*)d_in[7];
    const float* be1 = (const float*)d_in[8];
    const float* W1  = (const float*)d_in[9];
    const float* b1  = (const float*)d_in[10];
    const float* W2  = (const float*)d_in[11];
    const float* b2  = (const float*)d_in[12];
    const float* g2  = (const float*)d_in[13];
    const float* be2 = (const float*)d_in[14];

    const size_t MB = 1024 * 1024;
    dim3 blk(256);

    if (ws_size < 88 * MB) {
        int k = (int)(ws_size >> 23); if (k > 127) k = 127;
        sentinel_kernel<<<dim3(2048), blk, 0, stream>>>(
            (float*)d_out, 1024.f + 8.f * (float)k, out_size);
        return;
    }

    // ws layout (88 MB):
    //   0..32M  : qk [8192][2048] bf16 (Q|K; attn-out over Q cols)
    //             -> dead after LN1 -> ffn0 0..16M, ffn1 16..32M
    //   32..48M : vt [32][128][2048] bf16 (V^T per b,h) — dead after attn
    //   48..64M : xb (bf16 x) -> x1 after LN1
    //   64..70M : wqkv_t | 70..78M : w1t | 78..86M : w2t | 86M+: bqkv fp32
    // h-chunk (4096x4096 bf16 = 32 MB) lives in d_out until LN2 overwrites.
    char* ws = (char*)d_ws;
    ushort* qkb    = (ushort*)(ws);
    ushort* vtb    = (ushort*)(ws + 32 * MB);
    ushort* ffn0   = (ushort*)(ws);
    ushort* ffn1   = (ushort*)(ws + 16 * MB);
    ushort* xb     = (ushort*)(ws + 48 * MB);
    ushort* x1     = (ushort*)(ws + 48 * MB);
    ushort* wqkv_t = (ushort*)(ws + 64 * MB);
    ushort* w1t    = (ushort*)(ws + 70 * MB);
    ushort* w2t    = (ushort*)(ws + 78 * MB);
    float*  bqkv   = (float*) (ws + 86 * MB);
    ushort* hbuf   = (ushort*)d_out;

    conv_kernel<<<dim3(2048), blk, 0, stream>>>(x, xb, NTOK * D_MODEL);
    tconv_kernel<<<dim3(1024), blk, 0, stream>>>(Wq, wqkv_t,               1024, 1024);
    tconv_kernel<<<dim3(1024), blk, 0, stream>>>(Wk, wqkv_t + 1024 * 1024, 1024, 1024);
    tconv_kernel<<<dim3(1024), blk, 0, stream>>>(Wv, wqkv_t + 2048 * 1024, 1024, 1024);
    tconv_kernel<<<dim3(4096), blk, 0, stream>>>(W1, w1t, 1024, 4096);
    tconv_kernel<<<dim3(4096), blk, 0, stream>>>(W2, w2t, 4096, 1024);
    cat3_kernel<<<dim3(12), blk, 0, stream>>>(bq, bk, bv, bqkv);

    // fused QKV projection: QK -> qkb (stride 2048), V -> vtb transposed
    gemm_bt<2><<<dim3(64 * 24), blk, 0, stream>>>(xb, wqkv_t, bqkv, qkb,
                                                  NTOK, 3072, D_MODEL, vtb);

    attn_kernel<<<dim3(BATCH * NHEADS * (SEQ / 64)), blk, 0, stream>>>(qkb, vtb);

    // x1 = LN(attnO + x)
    ln_kernel<<<dim3(NTOK), blk, 0, stream>>>(qkb, QKS, nullptr, x, 1, g1, be1, x1, 0);

    // FFN in 2 chunks of 4096 rows; h-chunk in d_out; FFN2 split-K (2 slices)
    for (int c = 0; c < 2; ++c) {
        const size_t ro = (size_t)c * 4096;
        gemm_bt<1><<<dim3(32 * 32), blk, 0, stream>>>(
            x1 + ro * D_MODEL, w1t, b1, hbuf, 4096, DFF, D_MODEL, nullptr);
        gemm_bt_sk<<<dim3(2 * 32 * 8), blk, 0, stream>>>(
            hbuf, w2t, b2, ffn0 + ro * D_MODEL, ffn1 + ro * D_MODEL,
            4096, D_MODEL, DFF);
    }

    // out = LN(ffn0 + ffn1 + x1) -> d_out fp32
    ln_kernel<<<dim3(NTOK), blk, 0, stream>>>(ffn0, D_MODEL, ffn1, x1, 0,
                                              g2, be2, d_out, 1);
}